// Round 11
// baseline (827.102 us; speedup 1.0000x reference)
//
#include <hip/hip_runtime.h>
#include <hip/hip_bf16.h>

// PointerNetwork: B=4096, L=10, IN=8, H=512, W=512. fp32 in/out, ws=256MiB.
// log_softmax over size-1 axes => hi==he==0. Surviving compute:
//   enc GRU, ew3 = h_enc @ w3^T, dec GRU, a4 = h_dec @ w4^T,
//   out_seq = tanh(ew3+a4)@v2, out_ori = h_dec @ wori[:,H:2H]^T + bori.
// Round 11: ZERO-COMMUNICATION recurrence. 128 blocks x 32 rows x 512 thr;
// each block owns all 512 h-cols for its rows => h stays in LDS (bf16,
// padded), no inter-block sync at all (round-10's 8x-duplicated device-scope
// h-exchange was the 24us/step floor). Weights streamed per-wave via
// global_load_lds (L2-resident). Encoder xg: r,z via K=32 zero-padded MFMA,
// n-gate x-part via LDS dot8 (kept separate until r known). Decoder xg
// packed bf16 in VGPRs. LDS ~143KB of 160KB.

#define B_   4096
#define L_   10
#define IN_  8
#define H_   512
#define H3_  1536
#define W_   512
#define ORI_BASE (B_ * L_ * L_)   // 409600

typedef __attribute__((ext_vector_type(8))) short s8v;
typedef __attribute__((ext_vector_type(4))) float f4v;

#define AS1 __attribute__((address_space(1)))
#define AS3 __attribute__((address_space(3)))

#define LOG2E  1.4426950408889634f
#define LOG2E2 2.8853900817779268f

__device__ __forceinline__ float sig_fast(float x) {
  float e = __builtin_amdgcn_exp2f(-x * LOG2E);
  return __builtin_amdgcn_rcpf(1.f + e);
}
__device__ __forceinline__ float tanh_fast(float x) {
  float e = __builtin_amdgcn_exp2f(x * LOG2E2);
  return 1.f - 2.f * __builtin_amdgcn_rcpf(e + 1.f);
}
__device__ __forceinline__ short f2bf(float f) {
  __hip_bfloat16 h = __float2bfloat16(f);
  return __builtin_bit_cast(short, h);
}
__device__ __forceinline__ float bf2f(short s) {
  __hip_bfloat16 h = __builtin_bit_cast(__hip_bfloat16, s);
  return __bfloat162float(h);
}
__device__ __forceinline__ void stc(float* p, float v) { *p = v; }
__device__ __forceinline__ void stc(short* p, float v) { *p = f2bf(v); }
__device__ __forceinline__ unsigned pk2(float a, float b) {
  return (unsigned)(unsigned short)f2bf(a) | ((unsigned)(unsigned short)f2bf(b) << 16);
}
__device__ __forceinline__ float upk(unsigned w, int hi) {
  return bf2f((short)(hi ? (w >> 16) : (w & 0xffff)));
}

// ---- fused fp32->bf16 conversion of all 6 tensors in one launch ----
__global__ __launch_bounds__(256) void convert_all(
    const float* __restrict__ s0, const float* __restrict__ s1,
    const float* __restrict__ s2, const float* __restrict__ s3,
    const float* __restrict__ s4, const float* __restrict__ s5,
    short* __restrict__ d0, short* __restrict__ d1, short* __restrict__ d2,
    short* __restrict__ d3, short* __restrict__ d4, short* __restrict__ d5)
{
  long i = (long)blockIdx.x * 256 + threadIdx.x;
  const float* s; short* d; long o;
  if      (i < 786432)  { s = s0; d = d0; o = i; }
  else if (i < 1572864) { s = s1; d = d1; o = i - 786432; }
  else if (i < 2359296) { s = s2; d = d2; o = i - 1572864; }
  else if (i < 2621440) { s = s3; d = d3; o = i - 2359296; }
  else if (i < 2883584) { s = s4; d = d4; o = i - 2621440; }
  else                  { s = s5; d = d5; o = i - 2883584; }
  d[o] = f2bf(s[o]);
}

// ---- fold embedding into encoder input weight; one wave per gate-row ----
// Outputs: Wcp (1024 x 32) bf16 for gates r,z (k>=8 zeroed for the K=32
// MFMA x-pass), WcN (512 x 8) bf16 for gate n, bc (1536) fp32 (incl enc_bih).
__global__ __launch_bounds__(256) void build_wc(
    const float* __restrict__ enc_wih, const float* __restrict__ emb_w,
    const float* __restrict__ emb_b, const float* __restrict__ enc_bih,
    short* __restrict__ Wcp, short* __restrict__ WcN, float* __restrict__ bc)
{
  __shared__ float se[H_ * IN_];
  __shared__ float sb[H_];
  const int tid = threadIdx.x;
  for (int i = tid; i < H_ * IN_; i += 256) se[i] = emb_w[i];
  for (int i = tid; i < H_; i += 256) sb[i] = emb_b[i];
  __syncthreads();
  int g = (blockIdx.x * 256 + tid) >> 6;   // 0..1535
  int lane = tid & 63;
  const float* wr = enc_wih + (long)g * H_ + lane * 8;
  float w8[8];
#pragma unroll
  for (int j = 0; j < 8; ++j) w8[j] = wr[j];
  float acc[9] = {};
#pragma unroll
  for (int kk = 0; kk < 8; ++kk) {
    int k = lane * 8 + kk;
#pragma unroll
    for (int j = 0; j < 8; ++j) acc[j] += w8[kk] * se[k * IN_ + j];
    acc[8] += w8[kk] * sb[k];
  }
#pragma unroll
  for (int j = 0; j < 9; ++j)
#pragma unroll
    for (int off = 32; off; off >>= 1) acc[j] += __shfl_down(acc[j], off, 64);
  if (lane == 0) {
    if (g < 1024) {
#pragma unroll
      for (int j = 0; j < 8; ++j) Wcp[g * 32 + j] = f2bf(acc[j]);
#pragma unroll
      for (int j = 8; j < 32; ++j) Wcp[g * 32 + j] = 0;   // zero pad (NaN-safe)
    } else {
#pragma unroll
      for (int j = 0; j < 8; ++j) WcN[(g - 1024) * 8 + j] = f2bf(acc[j]);
    }
    bc[g] = acc[8] + enc_bih[g];
  }
}

// ---- the whole recurrence: zero-communication persistent blocks ----
// 128 blocks x 512 threads; block owns rows [bid*32, +32), ALL 512 h-cols.
// Wave w owns h-cols [w*64, +64). h lives in hL (bf16, stride 520).
__global__ __launch_bounds__(512, 2) void recurrence(
    const float* __restrict__ items,    // (B,L,IN) fp32
    const short* __restrict__ decb,     // (B,H) bf16
    const short* __restrict__ whh_e, const float* __restrict__ bhh_e,
    const short* __restrict__ whh_d, const float* __restrict__ bhh_d,
    const short* __restrict__ wih_d, const float* __restrict__ bih_d,
    const short* __restrict__ Wcp, const short* __restrict__ WcNg,
    const float* __restrict__ bc,
    short* __restrict__ enc_hist,       // (11,B,H) bf16; slices 1..10 written
    short* __restrict__ dec_hist)       // (10,B,H) bf16
{
  __shared__ short hL[32 * 520];       // 33.3 KB h (bf16, padded)
  __shared__ short Bs[8 * 6144];       // 96 KB: 12 KB per-wave B staging
  __shared__ short itemsA[32 * 32];    // 2 KB zero-padded A for x-MFMA
  __shared__ short WcN[512 * 8];       // 8 KB n-gate folded emb weight
  __shared__ float itemsF[32 * 8];     // 1 KB items fp32 for n-gate dot

  const int tid = threadIdx.x;
  const int wave = tid >> 6, lane = tid & 63;
  const int r16 = lane & 15, quad = lane >> 4;
  const int c0w = wave * 64;
  const long row0 = (long)blockIdx.x * 32;
  const long BH = (long)B_ * H_;
  short* wBs = Bs + wave * 6144;

  // per-thread bias constants (col depends on cf)
  float bceR[4], bceZ[4], bcN4[4], behN[4], bdR[4], bdZ[4], bdN[4];
#pragma unroll
  for (int cf = 0; cf < 4; ++cf) {
    int col = c0w + cf * 16 + r16;
    bceR[cf] = bc[col] + bhh_e[col];
    bceZ[cf] = bc[col + 512] + bhh_e[col + 512];
    bcN4[cf] = bc[col + 1024];
    behN[cf] = bhh_e[col + 1024];
    bdR[cf] = bhh_d[col];
    bdZ[cf] = bhh_d[col + 512];
    bdN[cf] = bhh_d[col + 1024];
  }

  // stage WcN (constant across steps)
  for (int i = tid; i < 512 * 8; i += 512) WcN[i] = WcNg[i];

  f4v acc[3][2][4];
  const f4v fz = {0.f, 0.f, 0.f, 0.f};
  auto zero_acc = [&]() {
#pragma unroll
    for (int g = 0; g < 3; ++g)
#pragma unroll
      for (int rf = 0; rf < 2; ++rf)
#pragma unroll
        for (int cf = 0; cf < 4; ++cf) acc[g][rf][cf] = fz;
  };

  // 3-gate K=512 pass: acc += hL(32xK) @ Wg[g*512+col]^T, per-wave B staging
  auto h_pass = [&](const short* __restrict__ Wg) {
    for (int k0i = 0; k0i < 16; ++k0i) {
      const int k0 = k0i << 5;
#pragma unroll
      for (int r = 0; r < 12; ++r) {           // 192 rows x 32 shorts
        int idx = r * 64 + lane;
        int m = idx >> 2, k8 = (idx & 3) * 8;
        int wrow = ((m >> 6) << 9) + c0w + (m & 63);
        __builtin_amdgcn_global_load_lds(
            (const AS1 void*)(Wg + (long)wrow * H_ + k0 + k8),
            (AS3 void*)(wBs + idx * 8), 16, 0, 0);
      }
      s8v a0 = *(const s8v*)&hL[r16 * 520 + k0 + quad * 8];
      s8v a1 = *(const s8v*)&hL[(16 + r16) * 520 + k0 + quad * 8];
      __asm__ __volatile__("s_waitcnt vmcnt(0)" ::: "memory");
#pragma unroll
      for (int g = 0; g < 3; ++g)
#pragma unroll
        for (int cf = 0; cf < 4; ++cf) {
          s8v bf = *(const s8v*)&wBs[(((g << 6) + (cf << 4) + r16) << 5) + quad * 8];
          acc[g][0][cf] = __builtin_amdgcn_mfma_f32_16x16x32_bf16(a0, bf, acc[g][0][cf], 0, 0, 0);
          acc[g][1][cf] = __builtin_amdgcn_mfma_f32_16x16x32_bf16(a1, bf, acc[g][1][cf], 0, 0, 0);
        }
    }
  };

  // ---- decoder xg (r,z,n) into packed bf16 regs: decb @ wih_d^T + bih ----
  for (int i = tid; i < 2048; i += 512) {      // decb rows -> hL (padded)
    int m = i >> 6, c8 = i & 63;
    *(s8v*)&hL[m * 520 + c8 * 8] = *(const s8v*)&decb[(row0 + m) * H_ + c8 * 8];
  }
  __syncthreads();
  zero_acc();
  h_pass(wih_d);
  unsigned xp[3][2][4][2];
#pragma unroll
  for (int g = 0; g < 3; ++g)
#pragma unroll
    for (int cf = 0; cf < 4; ++cf) {
      float bih = bih_d[g * 512 + c0w + cf * 16 + r16];
#pragma unroll
      for (int rf = 0; rf < 2; ++rf) {
        xp[g][rf][cf][0] = pk2(acc[g][rf][cf][0] + bih, acc[g][rf][cf][1] + bih);
        xp[g][rf][cf][1] = pk2(acc[g][rf][cf][2] + bih, acc[g][rf][cf][3] + bih);
      }
    }
  __syncthreads();                             // all hL reads (MFMA) done
  {                                            // h0 = 0
    int* hz = (int*)hL;
    for (int i = tid; i < 32 * 520 / 2; i += 512) hz[i] = 0;
  }

  // ---- Encoder: 10 steps ----
  for (int t = 0; t < L_; ++t) {
    for (int i = tid; i < 1024; i += 512) {    // itemsA: 32x32 bf16, k>=8 zero
      int m = i >> 5, k = i & 31;
      itemsA[i] = (k < IN_) ? f2bf(items[(row0 + m) * (L_ * IN_) + t * IN_ + k])
                            : (short)0;
    }
    if (tid < 256) {                           // itemsF: 32x8 fp32
      int m = tid >> 3, j = tid & 7;
      itemsF[tid] = items[(row0 + m) * (L_ * IN_) + t * IN_ + j];
    }
    __syncthreads();
    zero_acc();
    {                                          // x-pass: gates r,z, K=32
#pragma unroll
      for (int r = 0; r < 8; ++r) {            // 128 rows x 32 shorts
        int idx = r * 64 + lane;
        int m = idx >> 2, k8 = (idx & 3) * 8;
        int wrow = ((m >> 6) << 9) + c0w + (m & 63);
        __builtin_amdgcn_global_load_lds(
            (const AS1 void*)(Wcp + wrow * 32 + k8),
            (AS3 void*)(wBs + idx * 8), 16, 0, 0);
      }
      s8v a0 = *(const s8v*)&itemsA[r16 * 32 + quad * 8];
      s8v a1 = *(const s8v*)&itemsA[(16 + r16) * 32 + quad * 8];
      __asm__ __volatile__("s_waitcnt vmcnt(0)" ::: "memory");
#pragma unroll
      for (int g = 0; g < 2; ++g)
#pragma unroll
        for (int cf = 0; cf < 4; ++cf) {
          s8v bf = *(const s8v*)&wBs[(((g << 6) + (cf << 4) + r16) << 5) + quad * 8];
          acc[g][0][cf] = __builtin_amdgcn_mfma_f32_16x16x32_bf16(a0, bf, acc[g][0][cf], 0, 0, 0);
          acc[g][1][cf] = __builtin_amdgcn_mfma_f32_16x16x32_bf16(a1, bf, acc[g][1][cf], 0, 0, 0);
        }
    }
    if (t > 0) h_pass(whh_e);
    __syncthreads();                           // all hL/itemsA reads done
    // epilogue: gate math, RMW hL (each (row,col) owned by one thread)
    {
      s8v wn8[4];
#pragma unroll
      for (int cf = 0; cf < 4; ++cf)
        wn8[cf] = *(const s8v*)&WcN[(c0w + cf * 16 + r16) * 8];
#pragma unroll
      for (int rf = 0; rf < 2; ++rf)
#pragma unroll
        for (int rg = 0; rg < 4; ++rg) {
          int row = rf * 16 + quad * 4 + rg;
          float it8[8];
#pragma unroll
          for (int j = 0; j < 8; ++j) it8[j] = itemsF[row * 8 + j];
#pragma unroll
          for (int cf = 0; cf < 4; ++cf) {
            float xn = bcN4[cf];
#pragma unroll
            for (int j = 0; j < 8; ++j) xn += it8[j] * bf2f(wn8[cf][j]);
            float r = sig_fast(acc[0][rf][cf][rg] + bceR[cf]);
            float z = sig_fast(acc[1][rf][cf][rg] + bceZ[cf]);
            float n = tanh_fast(xn + r * (acc[2][rf][cf][rg] + behN[cf]));
            int ho = row * 520 + c0w + cf * 16 + r16;
            float hv = (1.f - z) * n + z * bf2f(hL[ho]);
            hL[ho] = f2bf(hv);
          }
        }
    }
    __syncthreads();
    short* dst = enc_hist + (long)(t + 1) * BH;  // coalesced copy-out
    for (int i = tid; i < 2048; i += 512) {
      int m = i >> 6, c8 = i & 63;
      *(s8v*)&dst[(row0 + m) * H_ + c8 * 8] = *(const s8v*)&hL[m * 520 + c8 * 8];
    }
  }

  // ---- Decoder: 10 steps (hL holds h10) ----
  for (int t = 0; t < L_; ++t) {
    zero_acc();
    h_pass(whh_d);
    __syncthreads();
#pragma unroll
    for (int rf = 0; rf < 2; ++rf)
#pragma unroll
      for (int rg = 0; rg < 4; ++rg) {
        int row = rf * 16 + quad * 4 + rg;
#pragma unroll
        for (int cf = 0; cf < 4; ++cf) {
          float xr = upk(xp[0][rf][cf][rg >> 1], rg & 1);
          float xz = upk(xp[1][rf][cf][rg >> 1], rg & 1);
          float xn = upk(xp[2][rf][cf][rg >> 1], rg & 1);
          float r = sig_fast(xr + acc[0][rf][cf][rg] + bdR[cf]);
          float z = sig_fast(xz + acc[1][rf][cf][rg] + bdZ[cf]);
          float n = tanh_fast(xn + r * (acc[2][rf][cf][rg] + bdN[cf]));
          int ho = row * 520 + c0w + cf * 16 + r16;
          float hv = (1.f - z) * n + z * bf2f(hL[ho]);
          hL[ho] = f2bf(hv);
        }
      }
    __syncthreads();
    short* dst = dec_hist + (long)t * BH;
    for (int i = tid; i < 2048; i += 512) {
      int m = i >> 6, c8 = i & 63;
      *(s8v*)&dst[(row0 + m) * H_ + c8 * 8] = *(const s8v*)&hL[m * 520 + c8 * 8];
    }
  }
}

// ---- bf16 MFMA GEMM (epilogue ew3/a4): C[M,N] = A @ B^T, bf16 out ----
__global__ __launch_bounds__(256) void gemm_bf16(
    const short* __restrict__ A, long lda,
    const short* __restrict__ Bw, long ldb,
    short* __restrict__ C, long ldc, int K)
{
  __shared__ short As[128 * 32];
  __shared__ short Bs[128 * 32];
  const int tid = threadIdx.x;
  const long row0 = (long)blockIdx.y * 128;
  const long col0 = (long)blockIdx.x * 128;
  const int wave = tid >> 6, lane = tid & 63;
  const int wm = (wave & 1) * 64, wn = (wave >> 1) * 64;
  const int r16 = lane & 15, quad = lane >> 4;
  f4v acc[4][4] = {};

  for (int k0 = 0; k0 < K; k0 += 32) {
#pragma unroll
    for (int r = 0; r < 2; ++r) {
      int idx = r * 256 + tid;
      int m = idx >> 2;
      int k8 = (idx & 3) * 8;
      __builtin_amdgcn_global_load_lds(
          (const AS1 void*)(A + (row0 + m) * lda + k0 + k8),
          (AS3 void*)(As + idx * 8), 16, 0, 0);
      __builtin_amdgcn_global_load_lds(
          (const AS1 void*)(Bw + (col0 + m) * ldb + k0 + k8),
          (AS3 void*)(Bs + idx * 8), 16, 0, 0);
    }
    __syncthreads();
    s8v af[4], bf[4];
#pragma unroll
    for (int i = 0; i < 4; ++i)
      af[i] = *(const s8v*)&As[(wm + i * 16 + r16) * 32 + quad * 8];
#pragma unroll
    for (int j = 0; j < 4; ++j)
      bf[j] = *(const s8v*)&Bs[(wn + j * 16 + r16) * 32 + quad * 8];
#pragma unroll
    for (int i = 0; i < 4; ++i)
#pragma unroll
      for (int j = 0; j < 4; ++j)
        acc[i][j] = __builtin_amdgcn_mfma_f32_16x16x32_bf16(af[i], bf[j], acc[i][j], 0, 0, 0);
    __syncthreads();
  }

#pragma unroll
  for (int i = 0; i < 4; ++i) {
    long rbase = row0 + wm + i * 16 + quad * 4;
#pragma unroll
    for (int j = 0; j < 4; ++j) {
      long c = col0 + wn + j * 16 + r16;
#pragma unroll
      for (int rg = 0; rg < 4; ++rg)
        stc(&C[(rbase + rg) * ldc + c], acc[i][j][rg]);
    }
  }
}

// ---- batched out_seq: one block per b; LDS-tile 10 enc-l + 10 dec-t rows ----
__global__ __launch_bounds__(256) void out_seq_all(
    const short* __restrict__ ew3,   // (Lenc, B, W) bf16
    const short* __restrict__ a4,    // (Ldec, B, W) bf16
    const float* __restrict__ v2,
    float* __restrict__ out)
{
  __shared__ short se[L_ * W_];
  __shared__ short sa[L_ * W_];
  const int b = blockIdx.x;
  const int tid = threadIdx.x;
  const int wave = tid >> 6, lane = tid & 63;
  for (int i = tid; i < L_ * W_ / 8; i += 256) {
    int l = i >> 6, c = i & 63;
    *(s8v*)(se + i * 8) = *(const s8v*)(ew3 + ((long)l * B_ + b) * W_ + c * 8);
    *(s8v*)(sa + i * 8) = *(const s8v*)(a4 + ((long)l * B_ + b) * W_ + c * 8);
  }
  float v2r[8];
#pragma unroll
  for (int j = 0; j < 8; ++j) v2r[j] = v2[lane * 8 + j];
  __syncthreads();

#pragma unroll
  for (int pp = 0; pp < 25; ++pp) {
    int p = wave * 25 + pp;       // 100 (t,l) pairs over 4 waves
    int t = p / L_, l = p - t * L_;
    s8v ev = *(const s8v*)(se + l * W_ + lane * 8);
    s8v av = *(const s8v*)(sa + t * W_ + lane * 8);
    float acc = 0.f;
#pragma unroll
    for (int j = 0; j < 8; ++j)
      acc += tanh_fast(bf2f(ev[j]) + bf2f(av[j])) * v2r[j];
#pragma unroll
    for (int off = 32; off; off >>= 1) acc += __shfl_down(acc, off, 64);
    if (lane == 0) out[((long)b * L_ + t) * L_ + l] = acc;
  }
}

// ---- batched out_ori: one wave per (b,t) ----
__global__ __launch_bounds__(256) void out_ori_all(
    const short* __restrict__ dh,    // (Ldec, B, H) bf16
    const float* __restrict__ wori, const float* __restrict__ bori,
    float* __restrict__ out)
{
  int wid = (blockIdx.x * 256 + threadIdx.x) >> 6;   // b*L + t
  int lane = threadIdx.x & 63;
  int b = wid / L_, t = wid - b * L_;
  s8v hv = *(const s8v*)(dh + ((long)t * B_ + b) * H_ + lane * 8);
  float hf[8];
#pragma unroll
  for (int j = 0; j < 8; ++j) hf[j] = bf2f(hv[j]);
  float res[6];
#pragma unroll
  for (int o = 0; o < 6; ++o) {
    const float* wr = wori + (long)o * H3_ + H_ + lane * 8;
    float acc = 0.f;
#pragma unroll
    for (int j = 0; j < 8; ++j) acc += hf[j] * wr[j];
#pragma unroll
    for (int off = 32; off; off >>= 1) acc += __shfl_down(acc, off, 64);
    res[o] = acc;
  }
  if (lane == 0) {
    float* po = out + ORI_BASE + ((long)b * L_ + t) * 6;
#pragma unroll
    for (int o = 0; o < 6; ++o) po[o] = res[o] + bori[o];
  }
}

extern "C" void kernel_launch(void* const* d_in, const int* in_sizes, int n_in,
                              void* d_out, int out_size, void* d_ws, size_t ws_size,
                              hipStream_t stream)
{
  const float* items   = (const float*)d_in[0];
  const float* dec_in  = (const float*)d_in[1];
  const float* emb_w   = (const float*)d_in[2];
  const float* emb_b   = (const float*)d_in[3];
  const float* enc_wih = (const float*)d_in[4];
  const float* enc_whh = (const float*)d_in[5];
  const float* enc_bih = (const float*)d_in[6];
  const float* enc_bhh = (const float*)d_in[7];
  const float* dec_wih = (const float*)d_in[8];
  const float* dec_whh = (const float*)d_in[9];
  const float* dec_bih = (const float*)d_in[10];
  const float* dec_bhh = (const float*)d_in[11];
  const float* w3      = (const float*)d_in[14];
  const float* w4      = (const float*)d_in[15];
  const float* v2      = (const float*)d_in[20];
  const float* wori    = (const float*)d_in[23];
  const float* bori    = (const float*)d_in[24];
  float* out = (float*)d_out;

  char* ws = (char*)d_ws;
  size_t off = 0;
  auto alloc = [&](size_t bytes) { size_t o = off; off += (bytes + 255) & ~255UL; return o; };
  short* Wcp      = (short*)(ws + alloc(1024 * 32 * 2));                 // 64 KiB
  short* WcNg     = (short*)(ws + alloc(512 * 8 * 2));                   // 8 KiB
  float* bc       = (float*)(ws + alloc(H3_ * 4));
  short* enc_hist = (short*)(ws + alloc((size_t)11 * B_ * H_ * 2));      // 46 MiB
  short* dec_hist = (short*)(ws + alloc((size_t)L_ * B_ * H_ * 2));      // 42 MiB
  short* ew3      = (short*)(ws + alloc((size_t)L_ * B_ * W_ * 2));      // 42 MiB
  short* a4       = (short*)(ws + alloc((size_t)L_ * B_ * W_ * 2));      // 42 MiB
  short* whh_e    = (short*)(ws + alloc((size_t)H3_ * H_ * 2));
  short* whh_d    = (short*)(ws + alloc((size_t)H3_ * H_ * 2));
  short* wih_d    = (short*)(ws + alloc((size_t)H3_ * H_ * 2));
  short* w3b      = (short*)(ws + alloc((size_t)W_ * H_ * 2));
  short* w4b      = (short*)(ws + alloc((size_t)W_ * H_ * 2));
  short* decb     = (short*)(ws + alloc((size_t)B_ * H_ * 2));

  // ---- prep: 2 launches, no memsets ----
  convert_all<<<19456, 256, 0, stream>>>(
      enc_whh, dec_whh, dec_wih, w3, w4, dec_in,
      whh_e, whh_d, wih_d, w3b, w4b, decb);
  build_wc<<<384, 256, 0, stream>>>(enc_wih, emb_w, emb_b, enc_bih, Wcp, WcNg, bc);

  // ---- recurrence: one launch, zero inter-block communication ----
  recurrence<<<128, 512, 0, stream>>>(
      items, decb, whh_e, enc_bhh, whh_d, dec_bhh, wih_d, dec_bih,
      Wcp, WcNg, bc, enc_hist, dec_hist);

  // ---- batched epilogue ----
  gemm_bf16<<<dim3(4, 320), 256, 0, stream>>>(
      enc_hist + (size_t)B_ * H_, H_, w3b, H_, ew3, W_, H_);
  gemm_bf16<<<dim3(4, 320), 256, 0, stream>>>(
      dec_hist, H_, w4b, H_, a4, W_, H_);
  out_seq_all<<<B_, 256, 0, stream>>>(ew3, a4, v2, out);
  out_ori_all<<<(B_ * L_) / 4, 256, 0, stream>>>(dec_hist, wori, bori, out);
}